// Round 14
// baseline (58.623 us; speedup 1.0000x reference)
//
#include <hip/hip_runtime.h>

// Actor MLP, B=262144 rows, fp32 in/out. Phases 2+3 on MFMA (16x16x32 bf16),
// A-side hi-only, B-side (W3/W4) split hi+lo. 64 rows/blk, 4 waves, (256,4).
// R13 post-mortem: coalesced x-staging paid, but reg-staged bf16 convert path
// (VMEM->VGPR->f2bf->pack->ds_write) is serial VALU at block head; x-rounding
// also doubled absmax. R14 single knob: x panel staged as raw f32 via
// global_load_lds DMA (8x 4KB issues, no VGPR/VALU); phase 1 reads f32 LDS.
// LDS 40448 B -> still 4 blocks/CU.

typedef float f4v  __attribute__((ext_vector_type(4)));
typedef float f16v __attribute__((ext_vector_type(16)));
typedef short s8v  __attribute__((ext_vector_type(8)));
typedef short s4v  __attribute__((ext_vector_type(4)));

constexpr int NG = 14, GI = 9, FH = 128, AD = 15;

__device__ __forceinline__ unsigned short f2bf(float f) {
    unsigned u = __builtin_bit_cast(unsigned, f);
    return (unsigned short)((u + 0x7fffu + ((u >> 16) & 1u)) >> 16);
}
__device__ __forceinline__ float bf2f(unsigned short h) {
    return __builtin_bit_cast(float, (unsigned)h << 16);
}

__device__ __forceinline__ void dma16(const void* g, void* l) {
    __builtin_amdgcn_global_load_lds(
        (const __attribute__((address_space(1))) unsigned*)g,
        (__attribute__((address_space(3))) unsigned*)l, 16, 0, 0);
}

// Pack W3 (57x128, K pad->64) and W4 (128x30, N pad->32) into per-lane
// B-fragment order: idx = ((kt*NT + nt)*64 + lane)*8 + j, element
// k = kt*32 + (lane>>4)*8 + j, n = nt*16 + (lane&15). hi/lo split-bf16.
__global__ void pack_kernel(const float* __restrict__ W3,
                            const float* __restrict__ W4,
                            unsigned short* __restrict__ pk) {
    unsigned short* W3h = pk;            // 8192 elems
    unsigned short* W3l = pk + 8192;     // 8192
    unsigned short* W4h = pk + 16384;    // 4096
    unsigned short* W4l = pk + 20480;    // 4096
    int t = blockIdx.x * 256 + threadIdx.x;
    if (t < 8192) {
        int j = t & 7, l = (t >> 3) & 63, nt = (t >> 9) & 7, kt = t >> 12;
        int k = kt * 32 + (l >> 4) * 8 + j, n = nt * 16 + (l & 15);
        float v = (k < 57) ? W3[k * FH + n] : 0.f;
        unsigned short h = f2bf(v);
        W3h[t] = h;
        W3l[t] = f2bf(v - bf2f(h));
    }
    if (t < 4096) {
        int j = t & 7, l = (t >> 3) & 63, nt = (t >> 9) & 1, kt = t >> 10;
        int k = kt * 32 + (l >> 4) * 8 + j, n = nt * 16 + (l & 15);
        float v = (n < 30) ? W4[k * 30 + n] : 0.f;
        unsigned short h = f2bf(v);
        W4h[t] = h;
        W4l[t] = f2bf(v - bf2f(h));
    }
}

__global__ __launch_bounds__(256, 4) void actor_fused(
    const float* __restrict__ x,     // [B,126]
    const float* __restrict__ sale,  // [B,1]
    const float* __restrict__ W1,    // [9,16]
    const float* __restrict__ b1,    // [16]
    const float* __restrict__ W2,    // [16,4]
    const float* __restrict__ b2,    // [4]
    const float* __restrict__ b3,    // [128]
    const float* __restrict__ b4,    // [30]
    const unsigned short* __restrict__ pk,
    float* __restrict__ om, float* __restrict__ os)
{
    // xf: x panel f32 [64][126] (32256 B, DMA-staged, linear).
    // sh: 8 KB, aliased in time (phase1/2: s_hi [64][64] bf16 swizzled;
    //     phase3: z_hi [32][128] bf16).
    __shared__ float xf[64 * 126];
    __shared__ unsigned short sh[4096];

    const int tid  = threadIdx.x;
    const int wv   = __builtin_amdgcn_readfirstlane(tid >> 6);  // wave 0..3
    const int lane = tid & 63;
    const int r    = lane;                 // row within block (phase 1)
    const int row0 = blockIdx.x * 64;

    // ---- stage x panel (64 rows x 126 f32 = 32256 B) via global_load_lds ----
    {
        const char* gsrc = (const char*)(x + (size_t)row0 * (NG * GI));
        char* ldst = (char*)xf;
        const int off = tid * 16;
        #pragma unroll
        for (int j = 0; j < 7; ++j)
            dma16(gsrc + j * 4096 + off, ldst + j * 4096 + off);
        if (tid < 224)                       // tail 3584 B
            dma16(gsrc + 7 * 4096 + off, ldst + 7 * 4096 + off);
    }
    __syncthreads();

    // ---------------- phase 1: VALU, groups split (4,4,3,3) ----------------
    const int gbase = __builtin_amdgcn_readfirstlane(4 * wv - (wv == 3 ? 1 : 0));
    const f16v* w1v = (const f16v*)W1;
    const f4v*  w2v = (const f4v*)W2;
    const f16v  b1v = *(const f16v*)b1;
    const f4v   b2v = *(const f4v*)b2;

    auto do_group = [&](int gg) {
        const float* xg = xf + r * 126 + gg * 9;
        float x0 = xg[0], x1 = xg[1], x2 = xg[2], x3 = xg[3], x4 = xg[4],
              x5 = xg[5], x6 = xg[6], x7 = xg[7], x8 = xg[8];
        f16v h = b1v;
        h += x0*w1v[0]; h += x1*w1v[1]; h += x2*w1v[2]; h += x3*w1v[3];
        h += x4*w1v[4]; h += x5*w1v[5]; h += x6*w1v[6]; h += x7*w1v[7];
        h += x8*w1v[8];
        h = __builtin_elementwise_max(h, (f16v)0.f);
        f4v s = b2v;
        s += h[0]*w2v[0];  s += h[1]*w2v[1];  s += h[2]*w2v[2];  s += h[3]*w2v[3];
        s += h[4]*w2v[4];  s += h[5]*w2v[5];  s += h[6]*w2v[6];  s += h[7]*w2v[7];
        s += h[8]*w2v[8];  s += h[9]*w2v[9];  s += h[10]*w2v[10]; s += h[11]*w2v[11];
        s += h[12]*w2v[12]; s += h[13]*w2v[13]; s += h[14]*w2v[14]; s += h[15]*w2v[15];
        s = __builtin_elementwise_max(s, (f4v)0.f);
        s4v hi = (s4v){(short)f2bf(s[0]), (short)f2bf(s[1]),
                       (short)f2bf(s[2]), (short)f2bf(s[3])};
        int byt = (r * 128 + gg * 8) ^ ((r & 7) << 4);   // k = gg*4 -> byte gg*8
        *(s4v*)((char*)sh + byt) = hi;
    };
    if (wv < 2) { do_group(gbase+0); do_group(gbase+1); do_group(gbase+2); do_group(gbase+3); }
    else        { do_group(gbase+0); do_group(gbase+1); do_group(gbase+2); }
    if (wv == 3) {
        float sv = sale[row0 + r];
        int byt = (r * 128 + 112) ^ ((r & 7) << 4);      // k=56
        *(unsigned short*)((char*)sh + byt) = f2bf(sv);
        #pragma unroll
        for (int kk = 57; kk < 64; ++kk) {               // zero K-pad
            int bb = (r * 128 + kk * 2) ^ ((r & 7) << 4);
            *(unsigned short*)((char*)sh + bb) = 0;
        }
    }
    __syncthreads();

    // ---------------- phase 2: z[64,128] = s[64,64] @ W3  (MFMA) ----------
    const s8v* W3hv = (const s8v*)pk;
    const s8v* W3lv = (const s8v*)(pk + 8192);
    s8v bh[2][2], bl[2][2];
    #pragma unroll
    for (int kt = 0; kt < 2; ++kt)
        #pragma unroll
        for (int ntl = 0; ntl < 2; ++ntl) {
            int nt = 2 * wv + ntl;
            bh[kt][ntl] = W3hv[(kt * 8 + nt) * 64 + lane];
            bl[kt][ntl] = W3lv[(kt * 8 + nt) * 64 + lane];
        }
    f4v acc[4][2];
    #pragma unroll
    for (int ntl = 0; ntl < 2; ++ntl) {
        float bv = b3[32 * wv + ntl * 16 + (lane & 15)];
        #pragma unroll
        for (int mt = 0; mt < 4; ++mt) acc[mt][ntl] = (f4v){bv, bv, bv, bv};
    }
    #pragma unroll
    for (int kt = 0; kt < 2; ++kt) {
        s8v ah[4];
        #pragma unroll
        for (int mt = 0; mt < 4; ++mt) {
            int rr = mt * 16 + (lane & 15);
            int byt = (rr * 128 + kt * 64 + (lane >> 4) * 16) ^ ((rr & 7) << 4);
            ah[mt] = *(const s8v*)((char*)sh + byt);
        }
        #pragma unroll
        for (int mt = 0; mt < 4; ++mt)
            #pragma unroll
            for (int ntl = 0; ntl < 2; ++ntl) {
                acc[mt][ntl] = __builtin_amdgcn_mfma_f32_16x16x32_bf16(ah[mt], bh[kt][ntl], acc[mt][ntl], 0, 0, 0);
                acc[mt][ntl] = __builtin_amdgcn_mfma_f32_16x16x32_bf16(ah[mt], bl[kt][ntl], acc[mt][ntl], 0, 0, 0);
            }
    }

    // ------- phase 3: out[64,30] = relu(z)[64,128] @ W4, in two row-halves --
    const s8v* W4hv = (const s8v*)(pk + 16384);
    const s8v* W4lv = (const s8v*)(pk + 20480);
    const int mtt  = __builtin_amdgcn_readfirstlane(wv >> 1);
    const int ntt  = __builtin_amdgcn_readfirstlane(wv & 1);
    const int ocol = ntt * 16 + (lane & 15);
    const float b4i = (ocol < 30) ? b4[ocol] : 0.f;

    #pragma unroll
    for (int half = 0; half < 2; ++half) {
        __syncthreads();   // h0: all phase-2 s-reads done; h1: h0 z-reads done
        // stage relu(z) rows [32*half, 32*half+32) as bf16 (hi only)
        #pragma unroll
        for (int mtl = 0; mtl < 2; ++mtl) {
            const int mt = 2 * half + mtl;
            #pragma unroll
            for (int ntl = 0; ntl < 2; ++ntl) {
                const int col = 32 * wv + ntl * 16 + (lane & 15);
                #pragma unroll
                for (int i = 0; i < 4; ++i) {
                    int rowl = mtl * 16 + (lane >> 4) * 4 + i;   // m89 C/D map
                    float v = fmaxf(acc[mt][ntl][i], 0.f);
                    int byt = (rowl * 256 + col * 2) ^ ((rowl & 7) << 4);
                    *(unsigned short*)((char*)sh + byt) = f2bf(v);
                }
            }
        }
        __syncthreads();
        f4v oa = (f4v){b4i, b4i, b4i, b4i};
        #pragma unroll
        for (int kt = 0; kt < 4; ++kt) {
            int rr = mtt * 16 + (lane & 15);
            int byt = (rr * 256 + kt * 64 + (lane >> 4) * 16) ^ ((rr & 7) << 4);
            s8v zh = *(const s8v*)((char*)sh + byt);
            s8v wh = W4hv[(kt * 2 + ntt) * 64 + lane];
            s8v wl = W4lv[(kt * 2 + ntt) * 64 + lane];
            oa = __builtin_amdgcn_mfma_f32_16x16x32_bf16(zh, wh, oa, 0, 0, 0);
            oa = __builtin_amdgcn_mfma_f32_16x16x32_bf16(zh, wl, oa, 0, 0, 0);
        }
        #pragma unroll
        for (int i = 0; i < 4; ++i) {
            int grow = row0 + half * 32 + mtt * 16 + (lane >> 4) * 4 + i;
            float v = oa[i];
            if (ocol < AD) {
                float tc = fminf(fmaxf(v, -20.f), 20.f);
                float e = __expf(2.f * tc);
                om[(size_t)grow * AD + ocol] = (e - 1.f) / (e + 1.f);
            } else if (ocol < 2 * AD) {
                os[(size_t)grow * AD + (ocol - AD)] = __expf(v);
            }
        }
    }
}

extern "C" void kernel_launch(void* const* d_in, const int* in_sizes, int n_in,
                              void* d_out, int out_size, void* d_ws, size_t ws_size,
                              hipStream_t stream) {
    const float* x    = (const float*)d_in[0];
    const float* sale = (const float*)d_in[1];
    const float* W1   = (const float*)d_in[2];
    const float* b1   = (const float*)d_in[3];
    const float* W2   = (const float*)d_in[4];
    const float* b2   = (const float*)d_in[5];
    const float* W3   = (const float*)d_in[6];
    const float* b3   = (const float*)d_in[7];
    const float* W4   = (const float*)d_in[8];
    const float* b4   = (const float*)d_in[9];

    int B = in_sizes[1];                       // sale_predictions is [B,1]
    float* om = (float*)d_out;                 // action_mean flat [B*15]
    float* os = om + (size_t)B * AD;           // action_std  flat [B*15]
    unsigned short* pk = (unsigned short*)d_ws;  // 24576 bf16 = 48 KB

    pack_kernel<<<32, 256, 0, stream>>>(W3, W4, pk);
    actor_fused<<<B / 64, 256, 0, stream>>>(x, sale, W1, b1, W2, b2,
                                            b3, b4, pk, om, os);
}

// Round 15
// 56.978 us; speedup vs baseline: 1.0289x; 1.0289x over previous
//
#include <hip/hip_runtime.h>

// Actor MLP, B=262144 rows, fp32 in/out. Phases 2+3 on MFMA (16x16x32 bf16),
// A-side hi-only, B-side (W3/W4) split hi+lo. 64 rows/blk, 4 waves, (256,4).
// R14 post-mortem: f32 DMA staging cost occupancy (LDS 40KB -> 4 blk/CU) for
// no VALU gain. R15: back to bf16 x (R13) + barrier restructure 6 -> 2:
//  - wave-private x staging (wave wv owns rows 16wv..16wv+15; no stage bar)
//  - single-pass phase 3: z[64][128]bf16 aliased over dead x region
// LDS 24576 B -> 6 blocks/CU kept.

typedef float f4v  __attribute__((ext_vector_type(4)));
typedef float f16v __attribute__((ext_vector_type(16)));
typedef short s8v  __attribute__((ext_vector_type(8)));
typedef short s4v  __attribute__((ext_vector_type(4)));

constexpr int NG = 14, GI = 9, FH = 128, AD = 15;

__device__ __forceinline__ unsigned short f2bf(float f) {
    unsigned u = __builtin_bit_cast(unsigned, f);
    return (unsigned short)((u + 0x7fffu + ((u >> 16) & 1u)) >> 16);
}
__device__ __forceinline__ float bf2f(unsigned short h) {
    return __builtin_bit_cast(float, (unsigned)h << 16);
}
__device__ __forceinline__ f4v load4u(const float* p) {
    f4v v; __builtin_memcpy(&v, p, 16); return v;
}

// Pack W3 (57x128, K pad->64) and W4 (128x30, N pad->32) into per-lane
// B-fragment order: idx = ((kt*NT + nt)*64 + lane)*8 + j, element
// k = kt*32 + (lane>>4)*8 + j, n = nt*16 + (lane&15). hi/lo split-bf16.
__global__ void pack_kernel(const float* __restrict__ W3,
                            const float* __restrict__ W4,
                            unsigned short* __restrict__ pk) {
    unsigned short* W3h = pk;            // 8192 elems
    unsigned short* W3l = pk + 8192;     // 8192
    unsigned short* W4h = pk + 16384;    // 4096
    unsigned short* W4l = pk + 20480;    // 4096
    int t = blockIdx.x * 256 + threadIdx.x;
    if (t < 8192) {
        int j = t & 7, l = (t >> 3) & 63, nt = (t >> 9) & 7, kt = t >> 12;
        int k = kt * 32 + (l >> 4) * 8 + j, n = nt * 16 + (l & 15);
        float v = (k < 57) ? W3[k * FH + n] : 0.f;
        unsigned short h = f2bf(v);
        W3h[t] = h;
        W3l[t] = f2bf(v - bf2f(h));
    }
    if (t < 4096) {
        int j = t & 7, l = (t >> 3) & 63, nt = (t >> 9) & 1, kt = t >> 10;
        int k = kt * 32 + (l >> 4) * 8 + j, n = nt * 16 + (l & 15);
        float v = (n < 30) ? W4[k * 30 + n] : 0.f;
        unsigned short h = f2bf(v);
        W4h[t] = h;
        W4l[t] = f2bf(v - bf2f(h));
    }
}

__global__ __launch_bounds__(256, 4) void actor_fused(
    const float* __restrict__ x,     // [B,126]
    const float* __restrict__ sale,  // [B,1]
    const float* __restrict__ W1,    // [9,16]
    const float* __restrict__ b1,    // [16]
    const float* __restrict__ W2,    // [16,4]
    const float* __restrict__ b2,    // [4]
    const float* __restrict__ b3,    // [128]
    const float* __restrict__ b4,    // [30]
    const unsigned short* __restrict__ pk,
    float* __restrict__ om, float* __restrict__ os)
{
    // xz: 16384 B. Life 1: x bf16 [64][126] (indices 0..8063). Life 2 (after
    //     bar 1): z bf16 [64][128] row-swizzled. Alias is safe: x reads all
    //     retire before bar 1; z writes all occur after bar 1.
    // sh: 8192 B: s bf16 [64 rows][64 k], row-swizzled.
    __shared__ unsigned short xz[8192];
    __shared__ unsigned short sh[4096];

    const int tid  = threadIdx.x;
    const int wv   = __builtin_amdgcn_readfirstlane(tid >> 6);  // wave 0..3
    const int lane = tid & 63;
    const int row0 = blockIdx.x * 64;

    // ---- wave-private x stage: rows [16wv, 16wv+16), 2016 floats -> bf16 ----
    {
        const float* xs = x + (size_t)(row0 + 16 * wv) * (NG * GI);
        unsigned* xw = (unsigned*)(xz + 16 * wv * 126);   // byte offset 4032*wv
        #pragma unroll
        for (int j = 0; j < 8; ++j) {
            int ci = j * 64 + lane;                        // f4v chunk index
            if (j < 7 || ci < 504) {
                f4v v = load4u(xs + 4 * ci);
                unsigned w0 = (unsigned)f2bf(v[0]) | ((unsigned)f2bf(v[1]) << 16);
                unsigned w1 = (unsigned)f2bf(v[2]) | ((unsigned)f2bf(v[3]) << 16);
                xw[2 * ci]     = w0;
                xw[2 * ci + 1] = w1;
            }
        }
    }
    // sale (k=56) + zero K-pad (k=57..63) for this wave's 16 rows
    if (lane < 16) {
        int r = 16 * wv + lane;
        float sv = sale[row0 + r];
        int byt = (r * 128 + 112) ^ ((r & 7) << 4);
        *(unsigned short*)((char*)sh + byt) = f2bf(sv);
        #pragma unroll
        for (int kk = 57; kk < 64; ++kk) {
            int bb = (r * 128 + kk * 2) ^ ((r & 7) << 4);
            *(unsigned short*)((char*)sh + bb) = 0;
        }
    }

    // ---- phase 1: wave-private rows; lane = (row = 16wv+(lane&15), q=lane>>4)
    //      groups {q, q+4, q+8} + {q+12 if q<2}  (covers 0..13) ----
    const int r1 = 16 * wv + (lane & 15);
    const int q  = lane >> 4;
    const f16v* w1v = (const f16v*)W1;
    const f4v*  w2v = (const f4v*)W2;
    const f16v  b1v = *(const f16v*)b1;
    const f4v   b2v = *(const f4v*)b2;

    auto do_group = [&](int gg) {
        const int hb = r1 * 126 + gg * 9;
        float x0 = bf2f(xz[hb + 0]), x1 = bf2f(xz[hb + 1]), x2 = bf2f(xz[hb + 2]);
        float x3 = bf2f(xz[hb + 3]), x4 = bf2f(xz[hb + 4]), x5 = bf2f(xz[hb + 5]);
        float x6 = bf2f(xz[hb + 6]), x7 = bf2f(xz[hb + 7]), x8 = bf2f(xz[hb + 8]);
        f16v h = b1v;
        h += x0*w1v[0]; h += x1*w1v[1]; h += x2*w1v[2]; h += x3*w1v[3];
        h += x4*w1v[4]; h += x5*w1v[5]; h += x6*w1v[6]; h += x7*w1v[7];
        h += x8*w1v[8];
        h = __builtin_elementwise_max(h, (f16v)0.f);
        f4v s = b2v;
        s += h[0]*w2v[0];  s += h[1]*w2v[1];  s += h[2]*w2v[2];  s += h[3]*w2v[3];
        s += h[4]*w2v[4];  s += h[5]*w2v[5];  s += h[6]*w2v[6];  s += h[7]*w2v[7];
        s += h[8]*w2v[8];  s += h[9]*w2v[9];  s += h[10]*w2v[10]; s += h[11]*w2v[11];
        s += h[12]*w2v[12]; s += h[13]*w2v[13]; s += h[14]*w2v[14]; s += h[15]*w2v[15];
        s = __builtin_elementwise_max(s, (f4v)0.f);
        s4v hi = (s4v){(short)f2bf(s[0]), (short)f2bf(s[1]),
                       (short)f2bf(s[2]), (short)f2bf(s[3])};
        int byt = (r1 * 128 + gg * 8) ^ ((r1 & 7) << 4);
        *(s4v*)((char*)sh + byt) = hi;
    };
    do_group(q); do_group(q + 4); do_group(q + 8);
    if (q < 2) do_group(q + 12);

    __syncthreads();   // bar 1: all s ready; x region now dead

    // ---------------- phase 2: z[64,128] = s[64,64] @ W3  (MFMA) ----------
    const s8v* W3hv = (const s8v*)pk;
    const s8v* W3lv = (const s8v*)(pk + 8192);
    s8v bh[2][2], bl[2][2];
    #pragma unroll
    for (int kt = 0; kt < 2; ++kt)
        #pragma unroll
        for (int ntl = 0; ntl < 2; ++ntl) {
            int nt = 2 * wv + ntl;
            bh[kt][ntl] = W3hv[(kt * 8 + nt) * 64 + lane];
            bl[kt][ntl] = W3lv[(kt * 8 + nt) * 64 + lane];
        }
    f4v acc[4][2];
    #pragma unroll
    for (int ntl = 0; ntl < 2; ++ntl) {
        float bv = b3[32 * wv + ntl * 16 + (lane & 15)];
        #pragma unroll
        for (int mt = 0; mt < 4; ++mt) acc[mt][ntl] = (f4v){bv, bv, bv, bv};
    }
    #pragma unroll
    for (int kt = 0; kt < 2; ++kt) {
        s8v ah[4];
        #pragma unroll
        for (int mt = 0; mt < 4; ++mt) {
            int rr = mt * 16 + (lane & 15);
            int byt = (rr * 128 + kt * 64 + (lane >> 4) * 16) ^ ((rr & 7) << 4);
            ah[mt] = *(const s8v*)((char*)sh + byt);
        }
        #pragma unroll
        for (int mt = 0; mt < 4; ++mt)
            #pragma unroll
            for (int ntl = 0; ntl < 2; ++ntl) {
                acc[mt][ntl] = __builtin_amdgcn_mfma_f32_16x16x32_bf16(ah[mt], bh[kt][ntl], acc[mt][ntl], 0, 0, 0);
                acc[mt][ntl] = __builtin_amdgcn_mfma_f32_16x16x32_bf16(ah[mt], bl[kt][ntl], acc[mt][ntl], 0, 0, 0);
            }
    }
    // stage relu(z) (all 64 rows) as bf16 into xz (row-swizzled, stride 256B)
    #pragma unroll
    for (int mt = 0; mt < 4; ++mt)
        #pragma unroll
        for (int ntl = 0; ntl < 2; ++ntl) {
            const int col = 32 * wv + ntl * 16 + (lane & 15);
            #pragma unroll
            for (int i = 0; i < 4; ++i) {
                int rowl = mt * 16 + (lane >> 4) * 4 + i;   // m89 C/D map
                float v = fmaxf(acc[mt][ntl][i], 0.f);
                int byt = (rowl * 256 + col * 2) ^ ((rowl & 7) << 4);
                *(unsigned short*)((char*)xz + byt) = f2bf(v);
            }
        }

    __syncthreads();   // bar 2: z ready

    // ---- phase 3 single pass: out[64,30] = z[64,128] @ W4 ----
    const s8v* W4hv = (const s8v*)(pk + 16384);
    const s8v* W4lv = (const s8v*)(pk + 20480);
    const int mq   = __builtin_amdgcn_readfirstlane(wv >> 1);  // row-half
    const int nq   = __builtin_amdgcn_readfirstlane(wv & 1);   // col-half
    const int ocol = nq * 16 + (lane & 15);
    const float b4i = (ocol < 30) ? b4[ocol] : 0.f;

    f4v oa0 = (f4v){b4i, b4i, b4i, b4i};
    f4v oa1 = oa0;
    #pragma unroll
    for (int kt = 0; kt < 4; ++kt) {
        s8v wh = W4hv[(kt * 2 + nq) * 64 + lane];
        s8v wl = W4lv[(kt * 2 + nq) * 64 + lane];
        int rr0 = mq * 32 + (lane & 15);
        int by0 = (rr0 * 256 + kt * 64 + (lane >> 4) * 16) ^ ((rr0 & 7) << 4);
        s8v z0 = *(const s8v*)((char*)xz + by0);
        oa0 = __builtin_amdgcn_mfma_f32_16x16x32_bf16(z0, wh, oa0, 0, 0, 0);
        oa0 = __builtin_amdgcn_mfma_f32_16x16x32_bf16(z0, wl, oa0, 0, 0, 0);
        int rr1 = rr0 + 16;
        int by1 = (rr1 * 256 + kt * 64 + (lane >> 4) * 16) ^ ((rr1 & 7) << 4);
        s8v z1 = *(const s8v*)((char*)xz + by1);
        oa1 = __builtin_amdgcn_mfma_f32_16x16x32_bf16(z1, wh, oa1, 0, 0, 0);
        oa1 = __builtin_amdgcn_mfma_f32_16x16x32_bf16(z1, wl, oa1, 0, 0, 0);
    }
    #pragma unroll
    for (int mi = 0; mi < 2; ++mi) {
        f4v oa = mi ? oa1 : oa0;
        #pragma unroll
        for (int i = 0; i < 4; ++i) {
            int grow = row0 + mq * 32 + mi * 16 + (lane >> 4) * 4 + i;
            float v = oa[i];
            if (ocol < AD) {
                float tc = fminf(fmaxf(v, -20.f), 20.f);
                float e = __expf(2.f * tc);
                om[(size_t)grow * AD + ocol] = (e - 1.f) / (e + 1.f);
            } else if (ocol < 2 * AD) {
                os[(size_t)grow * AD + (ocol - AD)] = __expf(v);
            }
        }
    }
}

extern "C" void kernel_launch(void* const* d_in, const int* in_sizes, int n_in,
                              void* d_out, int out_size, void* d_ws, size_t ws_size,
                              hipStream_t stream) {
    const float* x    = (const float*)d_in[0];
    const float* sale = (const float*)d_in[1];
    const float* W1   = (const float*)d_in[2];
    const float* b1   = (const float*)d_in[3];
    const float* W2   = (const float*)d_in[4];
    const float* b2   = (const float*)d_in[5];
    const float* W3   = (const float*)d_in[6];
    const float* b3   = (const float*)d_in[7];
    const float* W4   = (const float*)d_in[8];
    const float* b4   = (const float*)d_in[9];

    int B = in_sizes[1];                       // sale_predictions is [B,1]
    float* om = (float*)d_out;                 // action_mean flat [B*15]
    float* os = om + (size_t)B * AD;           // action_std  flat [B*15]
    unsigned short* pk = (unsigned short*)d_ws;  // 24576 bf16 = 48 KB

    pack_kernel<<<32, 256, 0, stream>>>(W3, W4, pk);
    actor_fused<<<B / 64, 256, 0, stream>>>(x, sale, W1, b1, W2, b2,
                                            b3, b4, pk, om, os);
}

// Round 17
// 54.574 us; speedup vs baseline: 1.0742x; 1.0440x over previous
//
#include <hip/hip_runtime.h>

// Actor MLP, B=262144 rows, fp32 in/out. Phases 2+3 on MFMA (16x16x32 bf16),
// A-side hi-only, B-side (W3/W4) split hi+lo. 64 rows/blk, 4 waves, (256,4),
// R15 2-barrier structure. R15 post-mortem: wall pinned ~56us across 3
// structures -> VALU-issue bound, dominated by phase-1 scalar f32 FMA.
// R17 (= R16 intent, compile-fixed): phase 1 in packed fp16 via native
// _Float16 ext_vector ops (contract to v_pk_fma_f16; no __half2 API).
// x staged as fp16 via v_cvt_pkrtz. W1/b1/W2 pre-packed as half2 pairs.

typedef float f4v  __attribute__((ext_vector_type(4)));
typedef short s8v  __attribute__((ext_vector_type(8)));
typedef short s4v  __attribute__((ext_vector_type(4)));
typedef _Float16 h2v __attribute__((ext_vector_type(2)));

constexpr int NG = 14, GI = 9, FH = 128, AD = 15;

__device__ __forceinline__ unsigned short f2bf(float f) {
    unsigned u = __builtin_bit_cast(unsigned, f);
    return (unsigned short)((u + 0x7fffu + ((u >> 16) & 1u)) >> 16);
}
__device__ __forceinline__ float bf2f(unsigned short h) {
    return __builtin_bit_cast(float, (unsigned)h << 16);
}
__device__ __forceinline__ f4v load4u(const float* p) {
    f4v v; __builtin_memcpy(&v, p, 16); return v;
}
__device__ __forceinline__ unsigned pkh(float a, float b) {
    return __builtin_bit_cast(unsigned, __builtin_amdgcn_cvt_pkrtz(a, b));
}

// pk layout (shorts): W3h[0,8192) W3l[8192,16384) W4h[16384,20480)
// W4l[20480,24576) W1p[24576,24720) b1p[24720,24736) W2p[24736,24800)
__global__ void pack_kernel(const float* __restrict__ W3,
                            const float* __restrict__ W4,
                            const float* __restrict__ W1,
                            const float* __restrict__ b1,
                            const float* __restrict__ W2,
                            unsigned short* __restrict__ pk) {
    unsigned short* W3h = pk;
    unsigned short* W3l = pk + 8192;
    unsigned short* W4h = pk + 16384;
    unsigned short* W4l = pk + 20480;
    unsigned* pk32 = (unsigned*)pk;
    int t = blockIdx.x * 256 + threadIdx.x;
    if (t < 8192) {
        int j = t & 7, l = (t >> 3) & 63, nt = (t >> 9) & 7, kt = t >> 12;
        int k = kt * 32 + (l >> 4) * 8 + j, n = nt * 16 + (l & 15);
        float v = (k < 57) ? W3[k * FH + n] : 0.f;
        unsigned short h = f2bf(v);
        W3h[t] = h;
        W3l[t] = f2bf(v - bf2f(h));
    }
    if (t < 4096) {
        int j = t & 7, l = (t >> 3) & 63, nt = (t >> 9) & 1, kt = t >> 10;
        int k = kt * 32 + (l >> 4) * 8 + j, n = nt * 16 + (l & 15);
        float v = (n < 30) ? W4[k * 30 + n] : 0.f;
        unsigned short h = f2bf(v);
        W4h[t] = h;
        W4l[t] = f2bf(v - bf2f(h));
    }
    if (t < 72) {   // W1 pairs: i=t>>3, j2=t&7 -> {W1[i][2j2], W1[i][2j2+1]}
        int i = t >> 3, j2 = t & 7;
        pk32[12288 + t] = pkh(W1[i * 16 + 2 * j2], W1[i * 16 + 2 * j2 + 1]);
    }
    if (t < 8)      // b1 pairs
        pk32[12360 + t] = pkh(b1[2 * t], b1[2 * t + 1]);
    if (t < 32) {   // W2 pairs: j2=t>>2, o=t&3 -> {W2[2j2][o], W2[2j2+1][o]}
        int j2 = t >> 2, o = t & 3;
        pk32[12368 + t] = pkh(W2[(2 * j2) * 4 + o], W2[(2 * j2 + 1) * 4 + o]);
    }
}

__global__ __launch_bounds__(256, 4) void actor_fused(
    const float* __restrict__ x,     // [B,126]
    const float* __restrict__ sale,  // [B,1]
    const float* __restrict__ b2,    // [4]
    const float* __restrict__ b3,    // [128]
    const float* __restrict__ b4,    // [30]
    const unsigned short* __restrict__ pk,
    float* __restrict__ om, float* __restrict__ os)
{
    // xz: 16384 B. Life 1: x fp16 [64][126]. Life 2 (after bar 1): z bf16
    //     [64][128] row-swizzled. sh: 8192 B: s bf16 [64][64] row-swizzled.
    __shared__ unsigned short xz[8192];
    __shared__ unsigned short sh[4096];

    const int tid  = threadIdx.x;
    const int wv   = __builtin_amdgcn_readfirstlane(tid >> 6);  // wave 0..3
    const int lane = tid & 63;
    const int row0 = blockIdx.x * 64;

    // ---- wave-private x stage: rows [16wv, 16wv+16) -> fp16 LDS ----
    {
        const float* xs = x + (size_t)(row0 + 16 * wv) * (NG * GI);
        unsigned* xw = (unsigned*)(xz + 16 * wv * 126);
        #pragma unroll
        for (int j = 0; j < 8; ++j) {
            int ci = j * 64 + lane;
            if (j < 7 || ci < 504) {
                f4v v = load4u(xs + 4 * ci);
                xw[2 * ci]     = pkh(v[0], v[1]);
                xw[2 * ci + 1] = pkh(v[2], v[3]);
            }
        }
    }
    // sale (k=56) + zero K-pad (k=57..63) for this wave's 16 rows
    if (lane < 16) {
        int r = 16 * wv + lane;
        float sv = sale[row0 + r];
        int byt = (r * 128 + 112) ^ ((r & 7) << 4);
        *(unsigned short*)((char*)sh + byt) = f2bf(sv);
        #pragma unroll
        for (int kk = 57; kk < 64; ++kk) {
            int bb = (r * 128 + kk * 2) ^ ((r & 7) << 4);
            *(unsigned short*)((char*)sh + bb) = 0;
        }
    }

    // ---- phase 1: packed fp16; row = 16wv+(lane&15), q = lane>>4 ----
    const int r1 = 16 * wv + (lane & 15);
    const int q  = lane >> 4;
    const h2v* w1p = (const h2v*)(pk + 24576);  // [9][8]
    const h2v* b1p = (const h2v*)(pk + 24720);  // [8]
    const h2v* w2p = (const h2v*)(pk + 24736);  // [8][4] idx j2*4+o
    const _Float16* xhp = (const _Float16*)xz;

    auto do_group = [&](int gg) {
        const int hb = r1 * 126 + gg * 9;
        h2v h0 = b1p[0], h1 = b1p[1], h2 = b1p[2], h3 = b1p[3],
            h4 = b1p[4], h5 = b1p[5], h6 = b1p[6], h7 = b1p[7];
        #pragma unroll
        for (int i = 0; i < 9; ++i) {
            _Float16 xs1 = xhp[hb + i];
            h2v xb = (h2v){xs1, xs1};
            const h2v* wr = w1p + i * 8;
            h0 += xb * wr[0]; h1 += xb * wr[1];
            h2 += xb * wr[2]; h3 += xb * wr[3];
            h4 += xb * wr[4]; h5 += xb * wr[5];
            h6 += xb * wr[6]; h7 += xb * wr[7];
        }
        const h2v zz = (h2v)(_Float16)0;
        h0 = __builtin_elementwise_max(h0, zz);
        h1 = __builtin_elementwise_max(h1, zz);
        h2 = __builtin_elementwise_max(h2, zz);
        h3 = __builtin_elementwise_max(h3, zz);
        h4 = __builtin_elementwise_max(h4, zz);
        h5 = __builtin_elementwise_max(h5, zz);
        h6 = __builtin_elementwise_max(h6, zz);
        h7 = __builtin_elementwise_max(h7, zz);
        float sv4[4];
        #pragma unroll
        for (int o = 0; o < 4; ++o) {
            h2v a2 = zz;
            a2 += h0 * w2p[0 * 4 + o];
            a2 += h1 * w2p[1 * 4 + o];
            a2 += h2 * w2p[2 * 4 + o];
            a2 += h3 * w2p[3 * 4 + o];
            a2 += h4 * w2p[4 * 4 + o];
            a2 += h5 * w2p[5 * 4 + o];
            a2 += h6 * w2p[6 * 4 + o];
            a2 += h7 * w2p[7 * 4 + o];
            float s = (float)a2[0] + (float)a2[1] + b2[o];
            sv4[o] = fmaxf(s, 0.f);
        }
        s4v hi = (s4v){(short)f2bf(sv4[0]), (short)f2bf(sv4[1]),
                       (short)f2bf(sv4[2]), (short)f2bf(sv4[3])};
        int byt = (r1 * 128 + gg * 8) ^ ((r1 & 7) << 4);
        *(s4v*)((char*)sh + byt) = hi;
    };
    do_group(q); do_group(q + 4); do_group(q + 8);
    if (q < 2) do_group(q + 12);

    __syncthreads();   // bar 1: all s ready; x region now dead

    // ---------------- phase 2: z[64,128] = s[64,64] @ W3  (MFMA) ----------
    const s8v* W3hv = (const s8v*)pk;
    const s8v* W3lv = (const s8v*)(pk + 8192);
    s8v bh[2][2], bl[2][2];
    #pragma unroll
    for (int kt = 0; kt < 2; ++kt)
        #pragma unroll
        for (int ntl = 0; ntl < 2; ++ntl) {
            int nt = 2 * wv + ntl;
            bh[kt][ntl] = W3hv[(kt * 8 + nt) * 64 + lane];
            bl[kt][ntl] = W3lv[(kt * 8 + nt) * 64 + lane];
        }
    f4v acc[4][2];
    #pragma unroll
    for (int ntl = 0; ntl < 2; ++ntl) {
        float bv = b3[32 * wv + ntl * 16 + (lane & 15)];
        #pragma unroll
        for (int mt = 0; mt < 4; ++mt) acc[mt][ntl] = (f4v){bv, bv, bv, bv};
    }
    #pragma unroll
    for (int kt = 0; kt < 2; ++kt) {
        s8v ah[4];
        #pragma unroll
        for (int mt = 0; mt < 4; ++mt) {
            int rr = mt * 16 + (lane & 15);
            int byt = (rr * 128 + kt * 64 + (lane >> 4) * 16) ^ ((rr & 7) << 4);
            ah[mt] = *(const s8v*)((char*)sh + byt);
        }
        #pragma unroll
        for (int mt = 0; mt < 4; ++mt)
            #pragma unroll
            for (int ntl = 0; ntl < 2; ++ntl) {
                acc[mt][ntl] = __builtin_amdgcn_mfma_f32_16x16x32_bf16(ah[mt], bh[kt][ntl], acc[mt][ntl], 0, 0, 0);
                acc[mt][ntl] = __builtin_amdgcn_mfma_f32_16x16x32_bf16(ah[mt], bl[kt][ntl], acc[mt][ntl], 0, 0, 0);
            }
    }
    // stage relu(z) (all 64 rows) as bf16 into xz (row-swizzled, stride 256B)
    #pragma unroll
    for (int mt = 0; mt < 4; ++mt)
        #pragma unroll
        for (int ntl = 0; ntl < 2; ++ntl) {
            const int col = 32 * wv + ntl * 16 + (lane & 15);
            #pragma unroll
            for (int i = 0; i < 4; ++i) {
                int rowl = mt * 16 + (lane >> 4) * 4 + i;   // m89 C/D map
                float v = fmaxf(acc[mt][ntl][i], 0.f);
                int byt = (rowl * 256 + col * 2) ^ ((rowl & 7) << 4);
                *(unsigned short*)((char*)xz + byt) = f2bf(v);
            }
        }

    __syncthreads();   // bar 2: z ready

    // ---- phase 3 single pass: out[64,30] = z[64,128] @ W4 ----
    const s8v* W4hv = (const s8v*)(pk + 16384);
    const s8v* W4lv = (const s8v*)(pk + 20480);
    const int mq   = __builtin_amdgcn_readfirstlane(wv >> 1);  // row-half
    const int nq   = __builtin_amdgcn_readfirstlane(wv & 1);   // col-half
    const int ocol = nq * 16 + (lane & 15);
    const float b4i = (ocol < 30) ? b4[ocol] : 0.f;

    f4v oa0 = (f4v){b4i, b4i, b4i, b4i};
    f4v oa1 = oa0;
    #pragma unroll
    for (int kt = 0; kt < 4; ++kt) {
        s8v wh = W4hv[(kt * 2 + nq) * 64 + lane];
        s8v wl = W4lv[(kt * 2 + nq) * 64 + lane];
        int rr0 = mq * 32 + (lane & 15);
        int by0 = (rr0 * 256 + kt * 64 + (lane >> 4) * 16) ^ ((rr0 & 7) << 4);
        s8v z0 = *(const s8v*)((char*)xz + by0);
        oa0 = __builtin_amdgcn_mfma_f32_16x16x32_bf16(z0, wh, oa0, 0, 0, 0);
        oa0 = __builtin_amdgcn_mfma_f32_16x16x32_bf16(z0, wl, oa0, 0, 0, 0);
        int rr1 = rr0 + 16;
        int by1 = (rr1 * 256 + kt * 64 + (lane >> 4) * 16) ^ ((rr1 & 7) << 4);
        s8v z1 = *(const s8v*)((char*)xz + by1);
        oa1 = __builtin_amdgcn_mfma_f32_16x16x32_bf16(z1, wh, oa1, 0, 0, 0);
        oa1 = __builtin_amdgcn_mfma_f32_16x16x32_bf16(z1, wl, oa1, 0, 0, 0);
    }
    #pragma unroll
    for (int mi = 0; mi < 2; ++mi) {
        f4v oa = mi ? oa1 : oa0;
        #pragma unroll
        for (int i = 0; i < 4; ++i) {
            int grow = row0 + mq * 32 + mi * 16 + (lane >> 4) * 4 + i;
            float v = oa[i];
            if (ocol < AD) {
                float tc = fminf(fmaxf(v, -20.f), 20.f);
                float e = __expf(2.f * tc);
                om[(size_t)grow * AD + ocol] = (e - 1.f) / (e + 1.f);
            } else if (ocol < 2 * AD) {
                os[(size_t)grow * AD + (ocol - AD)] = __expf(v);
            }
        }
    }
}

extern "C" void kernel_launch(void* const* d_in, const int* in_sizes, int n_in,
                              void* d_out, int out_size, void* d_ws, size_t ws_size,
                              hipStream_t stream) {
    const float* x    = (const float*)d_in[0];
    const float* sale = (const float*)d_in[1];
    const float* W1   = (const float*)d_in[2];
    const float* b1   = (const float*)d_in[3];
    const float* W2   = (const float*)d_in[4];
    const float* b2   = (const float*)d_in[5];
    const float* W3   = (const float*)d_in[6];
    const float* b3   = (const float*)d_in[7];
    const float* W4   = (const float*)d_in[8];
    const float* b4   = (const float*)d_in[9];

    int B = in_sizes[1];                       // sale_predictions is [B,1]
    float* om = (float*)d_out;                 // action_mean flat [B*15]
    float* os = om + (size_t)B * AD;           // action_std  flat [B*15]
    unsigned short* pk = (unsigned short*)d_ws;  // 24800 shorts = 49.6 KB

    pack_kernel<<<32, 256, 0, stream>>>(W3, W4, W1, b1, W2, pk);
    actor_fused<<<B / 64, 256, 0, stream>>>(x, sale, b2, b3, b4, pk, om, os);
}

// Round 18
// 50.011 us; speedup vs baseline: 1.1722x; 1.0913x over previous
//
#include <hip/hip_runtime.h>

// Actor MLP, B=262144 rows, fp32 in/out. Phases 2+3 on MFMA (16x16x32 bf16),
// A-side hi-only, B-side (W3/W4) split hi+lo. 64 rows/blk, 4 waves, (256,4),
// 2-barrier structure, fp16 packed phase 1.
// R18: z staged in C/D-native [4k][16row] tiles -> per (mt,ntl) the lane's 4
// acc rows are 8 contiguous bytes: 2x v_cvt_pk_bf16_f32 + ds_write_b64
// (was 4x (fmax+3-inst f2bf+ds_write_u16)). Phase-3 A-frags read back with
// ds_read_b64_tr_b16 (HW transpose; tile order gives k=(lane>>4)*8+j matching
// packed-B k-rule). Rule #18: lgkmcnt(0)+sched_barrier(0) before MFMAs.

typedef float f4v  __attribute__((ext_vector_type(4)));
typedef short s8v  __attribute__((ext_vector_type(8)));
typedef _Float16 h2v __attribute__((ext_vector_type(2)));
typedef unsigned u2v __attribute__((ext_vector_type(2)));
typedef unsigned u4v __attribute__((ext_vector_type(4)));

constexpr int NG = 14, GI = 9, FH = 128, AD = 15;

__device__ __forceinline__ unsigned short f2bf(float f) {
    unsigned u = __builtin_bit_cast(unsigned, f);
    return (unsigned short)((u + 0x7fffu + ((u >> 16) & 1u)) >> 16);
}
__device__ __forceinline__ float bf2f(unsigned short h) {
    return __builtin_bit_cast(float, (unsigned)h << 16);
}
__device__ __forceinline__ f4v load4u(const float* p) {
    f4v v; __builtin_memcpy(&v, p, 16); return v;
}
__device__ __forceinline__ unsigned pkh(float a, float b) {
    return __builtin_bit_cast(unsigned, __builtin_amdgcn_cvt_pkrtz(a, b));
}
__device__ __forceinline__ unsigned pkbf(float a, float b) {
    unsigned r;
    asm("v_cvt_pk_bf16_f32 %0, %1, %2" : "=v"(r) : "v"(a), "v"(b));
    return r;
}

// pk layout (shorts): W3h[0,8192) W3l[8192,16384) W4h[16384,20480)
// W4l[20480,24576) W1p[24576,24720) b1p[24720,24736) W2p[24736,24800)
__global__ void pack_kernel(const float* __restrict__ W3,
                            const float* __restrict__ W4,
                            const float* __restrict__ W1,
                            const float* __restrict__ b1,
                            const float* __restrict__ W2,
                            unsigned short* __restrict__ pk) {
    unsigned short* W3h = pk;
    unsigned short* W3l = pk + 8192;
    unsigned short* W4h = pk + 16384;
    unsigned short* W4l = pk + 20480;
    unsigned* pk32 = (unsigned*)pk;
    int t = blockIdx.x * 256 + threadIdx.x;
    if (t < 8192) {
        int j = t & 7, l = (t >> 3) & 63, nt = (t >> 9) & 7, kt = t >> 12;
        int k = kt * 32 + (l >> 4) * 8 + j, n = nt * 16 + (l & 15);
        float v = (k < 57) ? W3[k * FH + n] : 0.f;
        unsigned short h = f2bf(v);
        W3h[t] = h;
        W3l[t] = f2bf(v - bf2f(h));
    }
    if (t < 4096) {
        int j = t & 7, l = (t >> 3) & 63, nt = (t >> 9) & 1, kt = t >> 10;
        int k = kt * 32 + (l >> 4) * 8 + j, n = nt * 16 + (l & 15);
        float v = (n < 30) ? W4[k * 30 + n] : 0.f;
        unsigned short h = f2bf(v);
        W4h[t] = h;
        W4l[t] = f2bf(v - bf2f(h));
    }
    if (t < 72) {   // W1 pairs: i=t>>3, j2=t&7 -> {W1[i][2j2], W1[i][2j2+1]}
        int i = t >> 3, j2 = t & 7;
        pk32[12288 + t] = pkh(W1[i * 16 + 2 * j2], W1[i * 16 + 2 * j2 + 1]);
    }
    if (t < 8)      // b1 pairs
        pk32[12360 + t] = pkh(b1[2 * t], b1[2 * t + 1]);
    if (t < 32) {   // W2 pairs: j2=t>>2, o=t&3 -> {W2[2j2][o], W2[2j2+1][o]}
        int j2 = t >> 2, o = t & 3;
        pk32[12368 + t] = pkh(W2[(2 * j2) * 4 + o], W2[(2 * j2 + 1) * 4 + o]);
    }
}

__global__ __launch_bounds__(256, 4) void actor_fused(
    const float* __restrict__ x,     // [B,126]
    const float* __restrict__ sale,  // [B,1]
    const float* __restrict__ b2,    // [4]
    const float* __restrict__ b3,    // [128]
    const float* __restrict__ b4,    // [30]
    const unsigned short* __restrict__ pk,
    float* __restrict__ om, float* __restrict__ os)
{
    // xz 16 KB. Life 1: x fp16 [64][126]. Life 2 (after bar 1): z bf16 in
    // tiled layout: elem(R,K) = (R>>4)*2048 + (K>>5)*512 + tau*64 + (K&3)*16
    // + (R&15), tau = (K&4 ? 4+((K&31)>>3) : (K&31)>>3).
    // sh 8 KB: s bf16 [64][64] row-swizzled (phase 2, unchanged).
    __shared__ unsigned short xz[8192];
    __shared__ unsigned short sh[4096];

    const int tid  = threadIdx.x;
    const int wv   = __builtin_amdgcn_readfirstlane(tid >> 6);  // wave 0..3
    const int lane = tid & 63;
    const int row0 = blockIdx.x * 64;

    // ---- wave-private x stage: rows [16wv, 16wv+16) -> fp16 LDS ----
    {
        const float* xs = x + (size_t)(row0 + 16 * wv) * (NG * GI);
        unsigned* xw = (unsigned*)(xz + 16 * wv * 126);
        #pragma unroll
        for (int j = 0; j < 8; ++j) {
            int ci = j * 64 + lane;
            if (j < 7 || ci < 504) {
                f4v v = load4u(xs + 4 * ci);
                xw[2 * ci]     = pkh(v[0], v[1]);
                xw[2 * ci + 1] = pkh(v[2], v[3]);
            }
        }
    }
    // sale (k=56) + zero K-pad (k=57..63) for this wave's 16 rows
    if (lane < 16) {
        int r = 16 * wv + lane;
        float sv = sale[row0 + r];
        int byt = (r * 128 + 112) ^ ((r & 7) << 4);
        *(unsigned short*)((char*)sh + byt) = f2bf(sv);
        #pragma unroll
        for (int kk = 57; kk < 64; ++kk) {
            int bb = (r * 128 + kk * 2) ^ ((r & 7) << 4);
            *(unsigned short*)((char*)sh + bb) = 0;
        }
    }

    // ---- phase 1: packed fp16; row = 16wv+(lane&15), q = lane>>4 ----
    const int r1 = 16 * wv + (lane & 15);
    const int q  = lane >> 4;
    const h2v* w1p = (const h2v*)(pk + 24576);  // [9][8]
    const h2v* b1p = (const h2v*)(pk + 24720);  // [8]
    const h2v* w2p = (const h2v*)(pk + 24736);  // [8][4] idx j2*4+o
    const _Float16* xhp = (const _Float16*)xz;

    auto do_group = [&](int gg) {
        const int hb = r1 * 126 + gg * 9;
        h2v h0 = b1p[0], h1 = b1p[1], h2 = b1p[2], h3 = b1p[3],
            h4 = b1p[4], h5 = b1p[5], h6 = b1p[6], h7 = b1p[7];
        #pragma unroll
        for (int i = 0; i < 9; ++i) {
            _Float16 xs1 = xhp[hb + i];
            h2v xb = (h2v){xs1, xs1};
            const h2v* wr = w1p + i * 8;
            h0 += xb * wr[0]; h1 += xb * wr[1];
            h2 += xb * wr[2]; h3 += xb * wr[3];
            h4 += xb * wr[4]; h5 += xb * wr[5];
            h6 += xb * wr[6]; h7 += xb * wr[7];
        }
        const h2v zz = (h2v)(_Float16)0;
        h0 = __builtin_elementwise_max(h0, zz);
        h1 = __builtin_elementwise_max(h1, zz);
        h2 = __builtin_elementwise_max(h2, zz);
        h3 = __builtin_elementwise_max(h3, zz);
        h4 = __builtin_elementwise_max(h4, zz);
        h5 = __builtin_elementwise_max(h5, zz);
        h6 = __builtin_elementwise_max(h6, zz);
        h7 = __builtin_elementwise_max(h7, zz);
        float sv4[4];
        #pragma unroll
        for (int o = 0; o < 4; ++o) {
            h2v a2 = zz;
            a2 += h0 * w2p[0 * 4 + o];
            a2 += h1 * w2p[1 * 4 + o];
            a2 += h2 * w2p[2 * 4 + o];
            a2 += h3 * w2p[3 * 4 + o];
            a2 += h4 * w2p[4 * 4 + o];
            a2 += h5 * w2p[5 * 4 + o];
            a2 += h6 * w2p[6 * 4 + o];
            a2 += h7 * w2p[7 * 4 + o];
            float s = (float)a2[0] + (float)a2[1] + b2[o];
            sv4[o] = fmaxf(s, 0.f);
        }
        unsigned p01 = pkbf(sv4[0], sv4[1]);
        unsigned p23 = pkbf(sv4[2], sv4[3]);
        int byt = (r1 * 128 + gg * 8) ^ ((r1 & 7) << 4);
        *(u2v*)((char*)sh + byt) = (u2v){p01, p23};
    };
    do_group(q); do_group(q + 4); do_group(q + 8);
    if (q < 2) do_group(q + 12);

    __syncthreads();   // bar 1: all s ready; x region now dead

    // ---------------- phase 2: z[64,128] = s[64,64] @ W3  (MFMA) ----------
    const s8v* W3hv = (const s8v*)pk;
    const s8v* W3lv = (const s8v*)(pk + 8192);
    s8v bh[2][2], bl[2][2];
    #pragma unroll
    for (int kt = 0; kt < 2; ++kt)
        #pragma unroll
        for (int ntl = 0; ntl < 2; ++ntl) {
            int nt = 2 * wv + ntl;
            bh[kt][ntl] = W3hv[(kt * 8 + nt) * 64 + lane];
            bl[kt][ntl] = W3lv[(kt * 8 + nt) * 64 + lane];
        }
    f4v acc[4][2];
    #pragma unroll
    for (int ntl = 0; ntl < 2; ++ntl) {
        float bv = b3[32 * wv + ntl * 16 + (lane & 15)];
        #pragma unroll
        for (int mt = 0; mt < 4; ++mt) acc[mt][ntl] = (f4v){bv, bv, bv, bv};
    }
    #pragma unroll
    for (int kt = 0; kt < 2; ++kt) {
        s8v ah[4];
        #pragma unroll
        for (int mt = 0; mt < 4; ++mt) {
            int rr = mt * 16 + (lane & 15);
            int byt = (rr * 128 + kt * 64 + (lane >> 4) * 16) ^ ((rr & 7) << 4);
            ah[mt] = *(const s8v*)((char*)sh + byt);
        }
        #pragma unroll
        for (int mt = 0; mt < 4; ++mt)
            #pragma unroll
            for (int ntl = 0; ntl < 2; ++ntl) {
                acc[mt][ntl] = __builtin_amdgcn_mfma_f32_16x16x32_bf16(ah[mt], bh[kt][ntl], acc[mt][ntl], 0, 0, 0);
                acc[mt][ntl] = __builtin_amdgcn_mfma_f32_16x16x32_bf16(ah[mt], bl[kt][ntl], acc[mt][ntl], 0, 0, 0);
            }
    }
    // stage relu(z) into C/D-native tiled layout: per (mt,ntl) the 4 rows are
    // contiguous -> 2 cvt_pk + 1 ds_write_b64. K = 32wv+ntl*16+(lane&15).
    #pragma unroll
    for (int mt = 0; mt < 4; ++mt)
        #pragma unroll
        for (int ntl = 0; ntl < 2; ++ntl) {
            int kk  = ntl * 16 + (lane & 15);       // K & 31 (chunk = wv)
            int tau = (kk & 4) ? 4 + (kk >> 3) : (kk >> 3);
            int eidx = mt * 2048 + wv * 512 + tau * 64 + (kk & 3) * 16
                     + ((lane >> 4) << 2);
            float v0 = fmaxf(acc[mt][ntl][0], 0.f);
            float v1 = fmaxf(acc[mt][ntl][1], 0.f);
            float v2 = fmaxf(acc[mt][ntl][2], 0.f);
            float v3 = fmaxf(acc[mt][ntl][3], 0.f);
            *(u2v*)(xz + eidx) = (u2v){pkbf(v0, v1), pkbf(v2, v3)};
        }

    __syncthreads();   // bar 2: z ready

    // ---- phase 3: out[64,30] = z @ W4; A-frags via ds_read_b64_tr_b16 ----
    const s8v* W4hv = (const s8v*)(pk + 16384);
    const s8v* W4lv = (const s8v*)(pk + 20480);
    const int mq   = __builtin_amdgcn_readfirstlane(wv >> 1);  // row-half
    const int nq   = __builtin_amdgcn_readfirstlane(wv & 1);   // col-half
    const int ocol = nq * 16 + (lane & 15);
    const float b4i = (ocol < 30) ? b4[ocol] : 0.f;

    s8v wh[4], wl[4];
    #pragma unroll
    for (int kt = 0; kt < 4; ++kt) {
        wh[kt] = W4hv[(kt * 2 + nq) * 64 + lane];
        wl[kt] = W4lv[(kt * 2 + nq) * 64 + lane];
    }
    // panels p0 = 2mq (rows mq*32..+15), p1 = 2mq+1; chunks c = 0..3
    unsigned base = (unsigned)(size_t)&xz[0] + (unsigned)(2 * mq) * 4096u
                  + (unsigned)(lane * 8);
    u2v f0[4][2], f1[4][2];
    #pragma unroll
    for (int c = 0; c < 4; ++c) {
        unsigned a0 = base + c * 1024;
        unsigned a1 = a0 + 4096;
        asm volatile("ds_read_b64_tr_b16 %0, %1" : "=v"(f0[c][0]) : "v"(a0));
        asm volatile("ds_read_b64_tr_b16 %0, %1 offset:512" : "=v"(f0[c][1]) : "v"(a0));
        asm volatile("ds_read_b64_tr_b16 %0, %1" : "=v"(f1[c][0]) : "v"(a1));
        asm volatile("ds_read_b64_tr_b16 %0, %1 offset:512" : "=v"(f1[c][1]) : "v"(a1));
    }
    asm volatile("s_waitcnt lgkmcnt(0)" ::: "memory");
    __builtin_amdgcn_sched_barrier(0);

    f4v oa0 = (f4v){b4i, b4i, b4i, b4i};
    f4v oa1 = oa0;
    #pragma unroll
    for (int kt = 0; kt < 4; ++kt) {
        s8v z0 = __builtin_bit_cast(s8v,
            (u4v){f0[kt][0][0], f0[kt][0][1], f0[kt][1][0], f0[kt][1][1]});
        s8v z1 = __builtin_bit_cast(s8v,
            (u4v){f1[kt][0][0], f1[kt][0][1], f1[kt][1][0], f1[kt][1][1]});
        oa0 = __builtin_amdgcn_mfma_f32_16x16x32_bf16(z0, wh[kt], oa0, 0, 0, 0);
        oa0 = __builtin_amdgcn_mfma_f32_16x16x32_bf16(z0, wl[kt], oa0, 0, 0, 0);
        oa1 = __builtin_amdgcn_mfma_f32_16x16x32_bf16(z1, wh[kt], oa1, 0, 0, 0);
        oa1 = __builtin_amdgcn_mfma_f32_16x16x32_bf16(z1, wl[kt], oa1, 0, 0, 0);
    }
    #pragma unroll
    for (int mi = 0; mi < 2; ++mi) {
        f4v oa = mi ? oa1 : oa0;
        #pragma unroll
        for (int i = 0; i < 4; ++i) {
            int grow = row0 + mq * 32 + mi * 16 + (lane >> 4) * 4 + i;
            float v = oa[i];
            if (ocol < AD) {
                float tc = fminf(fmaxf(v, -20.f), 20.f);
                float e = __expf(2.f * tc);
                om[(size_t)grow * AD + ocol] = (e - 1.f) / (e + 1.f);
            } else if (ocol < 2 * AD) {
                os[(size_t)grow * AD + (ocol - AD)] = __expf(v);
            }
        }
    }
}

extern "C" void kernel_launch(void* const* d_in, const int* in_sizes, int n_in,
                              void* d_out, int out_size, void* d_ws, size_t ws_size,
                              hipStream_t stream) {
    const float* x    = (const float*)d_in[0];
    const float* sale = (const float*)d_in[1];
    const float* W1   = (const float*)d_in[2];
    const float* b1   = (const float*)d_in[3];
    const float* W2   = (const float*)d_in[4];
    const float* b2   = (const float*)d_in[5];
    const float* W3   = (const float*)d_in[6];
    const float* b3   = (const float*)d_in[7];
    const float* W4   = (const float*)d_in[8];
    const float* b4   = (const float*)d_in[9];

    int B = in_sizes[1];                       // sale_predictions is [B,1]
    float* om = (float*)d_out;                 // action_mean flat [B*15]
    float* os = om + (size_t)B * AD;           // action_std  flat [B*15]
    unsigned short* pk = (unsigned short*)d_ws;  // 24800 shorts = 49.6 KB

    pack_kernel<<<32, 256, 0, stream>>>(W3, W4, W1, b1, W2, pk);
    actor_fused<<<B / 64, 256, 0, stream>>>(x, sale, b2, b3, b4, pk, om, os);
}